// Round 8
// baseline (58.528 us; speedup 1.0000x reference)
//
#include <hip/hip_runtime.h>

// d2 (B=32, L=2048, K=512) fp32.
// z_t = clip(0.9*z_{t-1} + 0.1*d2_t, 0, 5), z_{-1}=0, scan over t.
//
// Chunked scan + truncated look-back warmup (W=64: absmax 3.9e-3 vs
// threshold 1.63e-2, stable across rounds).
//
// Empirical law (r1-r6, 6 configs): dur = logical bytes / ~6.1 TB/s.
// Width, TLP (512..4096 waves), prefetch depth: all null. Only traffic
// moves time. Writes fixed 134 MB; reads = 134 * (1 + (NC-1)*W/L).
//
// Round-7: NC=2 (C=1024) -> one warmup boundary, 272.6 MB logical
// (1.6% above the NC=1 floor of 268 MB, without the 1-wave/CU latency
// risk). 32768 threads = 512 waves; block=64 so the two chunk lengths
// (1024 vs 1088 iters) interleave across CUs for load balance.
// unroll 32 -> 8 KB/wave in flight, 16 KB/CU at 2 waves/CU.

constexpr int B  = 32;
constexpr int L  = 2048;
constexpr int K  = 512;
constexpr int NC = 2;            // chunks along L
constexpr int C  = L / NC;       // 1024
constexpr int W  = 64;           // warmup steps (0.9^64 ~ 1.2e-3)

__global__ __launch_bounds__(64)
void ema_nc2_kernel(const float* __restrict__ d2, float* __restrict__ out) {
    const float lam = 0.9f, om = 0.1f, zmax = 5.0f;

    int tid = blockIdx.x * blockDim.x + threadIdx.x;   // B*NC*K = 32768
    int k   = tid & (K - 1);
    int bc  = tid >> 9;          // / K
    int c   = bc & (NC - 1);
    int b   = bc >> 1;           // / NC

    const float* in = d2  + (size_t)b * L * K + k;
    float*       o  = out + (size_t)b * L * K + k;

    int t0 = c * C;
    int tw = t0 - W;
    if (tw < 0) tw = 0;

    float z = 0.0f;

    // warmup (no stores): 0 or 64 iters = 2 unroll blocks
    #pragma unroll 32
    for (int t = tw; t < t0; ++t) {
        float d = in[(size_t)t * K];
        z = fminf(fmaxf(lam * z + om * d, 0.0f), zmax);
    }

    // main chunk: 1024 iters = 32 unroll blocks
    #pragma unroll 32
    for (int t = t0; t < t0 + C; ++t) {
        float d = in[(size_t)t * K];
        z = fminf(fmaxf(lam * z + om * d, 0.0f), zmax);
        o[(size_t)t * K] = z;
    }
}

extern "C" void kernel_launch(void* const* d_in, const int* in_sizes, int n_in,
                              void* d_out, int out_size, void* d_ws, size_t ws_size,
                              hipStream_t stream) {
    const float* d2 = (const float*)d_in[0];
    float* out = (float*)d_out;

    int total = B * NC * K;                 // 32768 threads
    int block = 64;
    int grid  = total / block;              // 512 blocks
    ema_nc2_kernel<<<grid, block, 0, stream>>>(d2, out);
}